// Round 14
// baseline (176.351 us; speedup 1.0000x reference)
//
#include <hip/hip_runtime.h>

#define N 1024
#define D 2048
#define P 8
#define F 9
#define KTOT (F * D)          // 18432
#define BM 128                // tile M = N = 128
#define BKT 32                // K per step (16x16x32 MFMA)
#define MARGIN 0.3f

typedef float f32x4 __attribute__((ext_vector_type(4)));
typedef short s16x8 __attribute__((ext_vector_type(8)));

#define GLOBAL_AS __attribute__((address_space(1)))
#define LDS_AS __attribute__((address_space(3)))

__device__ __forceinline__ const float* feat_row(const float* __restrict__ g,
                                                 const float* __restrict__ p,
                                                 int i, int f) {
    return (f == 0) ? (g + (size_t)i * D)
                    : (p + ((size_t)i * P + (f - 1)) * D);
}

__device__ __forceinline__ unsigned f2bf(float x) {
    unsigned u = __float_as_uint(x);
    return (u + 0x7fffu + ((u >> 16) & 1u)) >> 16;   // RNE
}

// One WAVE per (i,f) row: sum-of-squares via shfl_xor (no barriers),
// scale by label/norm, convert to bf16, store V[(i*F+f)*D + k].
__global__ __launch_bounds__(256)
void pack_kernel(const float* __restrict__ gfeat,
                 const float* __restrict__ pfeat,
                 const float* __restrict__ plab,
                 unsigned short* __restrict__ V) {
    const int wid = (blockIdx.x << 2) | (threadIdx.x >> 6);  // row index i*F+f
    const int lane = threadIdx.x & 63;
    const int i = wid / F, f = wid % F;
    const float* src = feat_row(gfeat, pfeat, i, f);
    const float4* s4 = (const float4*)src;
    float4 a[4][2];
    #pragma unroll
    for (int q = 0; q < 4; ++q) {
        a[q][0] = s4[(q * 64 + lane) * 2];
        a[q][1] = s4[(q * 64 + lane) * 2 + 1];
    }
    float ss = 0.f;
    #pragma unroll
    for (int q = 0; q < 4; ++q)
        #pragma unroll
        for (int h = 0; h < 2; ++h)
            ss += a[q][h].x * a[q][h].x + a[q][h].y * a[q][h].y
                + a[q][h].z * a[q][h].z + a[q][h].w * a[q][h].w;
    #pragma unroll
    for (int m = 32; m > 0; m >>= 1) ss += __shfl_xor(ss, m, 64);
    const float ls = (f == 0) ? 1.0f : plab[i * P + (f - 1)];
    const float inv = ls / (sqrtf(ss) + 1e-12f);
    unsigned short* dst = V + (size_t)wid * D;
    #pragma unroll
    for (int q = 0; q < 4; ++q) {
        uint4 o;
        o.x = f2bf(a[q][0].x * inv) | (f2bf(a[q][0].y * inv) << 16);
        o.y = f2bf(a[q][0].z * inv) | (f2bf(a[q][0].w * inv) << 16);
        o.z = f2bf(a[q][1].x * inv) | (f2bf(a[q][1].y * inv) << 16);
        o.w = f2bf(a[q][1].z * inv) | (f2bf(a[q][1].w * inv) << 16);
        *(uint4*)&dst[(size_t)(q * 64 + lane) * 8] = o;
    }
}

// C = V * V^T, bf16 MFMA, 128x128 tile, runtime split-K, per-slice STORES.
// Round-11-verified inner structure (45.6 us, SQ_LDS_BANK_CONFLICT = 0):
// SYMMETRY 36 upper-triangle tiles/slice, mirror-stored; XCD-chunked swizzle;
// T2 XOR-swizzle lane-linear staging; THREE LDS buffers (48 KB -> 3/CU
// LDS-cap), depth-2 counted-vmcnt prefetch, 2 barriers/step.
// Residency ladder (rounds 8-13): 2 blocks/CU -> 54-55 us; 2.25 -> 45.5 us.
// This round probes 3.375 slots/CU via S=24 (host-gated on ws_size).
__global__ __launch_bounds__(256)
void gemm_kernel(const unsigned short* __restrict__ V,
                 float* __restrict__ part, int ks) {
    __shared__ short As[3][BM * BKT];   // 3 x 8 KB
    __shared__ short Bs[3][BM * BKT];   // 3 x 8 KB  (48 KB total)

    // bijective XCD swizzle (nwg = 36*S, divisible by 8 for S=8/16/24)
    const int nwg = gridDim.x * gridDim.y;
    const int l = blockIdx.x + gridDim.x * blockIdx.y;
    const int q = nwg >> 3;
    const int wg = (l & 7) * q + (l >> 3);
    const int t36 = wg % 36;          // upper-triangle tile index
    const int bz = wg / 36;           // K-slice

    // t36 -> (by, bx) with by <= bx; row by holds (8-by) tiles
    int by = 0, rem = t36;
    while (rem >= 8 - by) { rem -= 8 - by; ++by; }
    const int bx = by + rem;

    const int t = threadIdx.x;
    const int wave = t >> 6, lane = t & 63;
    const int i0 = by * BM;
    const int j0 = bx * BM;
    const int kbase = bz * ks;
    const int nsteps = ks >> 5;      // ks/32: 24 (S=24), 36 (S=16), 72 (S=8)

    // staging: thread t -> row t>>2 (and +64), slot t&3, source chunk XOR'd
    const int srow = t >> 2;
    const int schunk = (t & 3) ^ ((t >> 3) & 3);
    const unsigned short* Ag = V + (size_t)(i0 + srow) * KTOT + kbase + schunk * 8;
    const unsigned short* Bg = V + (size_t)(j0 + srow) * KTOT + kbase + schunk * 8;

    // fragment read: chunk K of row R at short offset R*32 + ((K^((R>>1)&3))*8)
    const int kq = lane >> 4;                       // K = 0..3
    const int rsw = ((lane & 15) >> 1) & 3;         // (R>>1)&3, uniform in m/n
    const int kk = (kq ^ rsw) * 8;                  // swizzled chunk offset (shorts)
    const int arow0 = (wave & 1) * 64 + (lane & 15);
    const int brow0 = (wave >> 1) * 64 + (lane & 15);

    f32x4 acc[4][4];
    #pragma unroll
    for (int m = 0; m < 4; ++m)
        #pragma unroll
        for (int n = 0; n < 4; ++n)
            acc[m][n] = (f32x4){0.f, 0.f, 0.f, 0.f};

#define STAGE(b) do {                                                          \
    __builtin_amdgcn_global_load_lds((const GLOBAL_AS void*)Ag,                \
        (LDS_AS void*)(&As[(b)][t * 8]), 16, 0, 0);                            \
    __builtin_amdgcn_global_load_lds((const GLOBAL_AS void*)(Ag + (size_t)64 * KTOT), \
        (LDS_AS void*)(&As[(b)][2048 + t * 8]), 16, 0, 0);                     \
    __builtin_amdgcn_global_load_lds((const GLOBAL_AS void*)Bg,                \
        (LDS_AS void*)(&Bs[(b)][t * 8]), 16, 0, 0);                            \
    __builtin_amdgcn_global_load_lds((const GLOBAL_AS void*)(Bg + (size_t)64 * KTOT), \
        (LDS_AS void*)(&Bs[(b)][2048 + t * 8]), 16, 0, 0);                     \
    Ag += BKT; Bg += BKT;                                                      \
} while (0)

#define COMPUTE(b) do {                                                        \
    s16x8 af[4], bf[4];                                                        \
    _Pragma("unroll")                                                          \
    for (int m = 0; m < 4; ++m)                                                \
        af[m] = *(const s16x8*)(&As[(b)][(arow0 + m * 16) * 32 + kk]);         \
    _Pragma("unroll")                                                          \
    for (int n = 0; n < 4; ++n)                                                \
        bf[n] = *(const s16x8*)(&Bs[(b)][(brow0 + n * 16) * 32 + kk]);         \
    _Pragma("unroll")                                                          \
    for (int m = 0; m < 4; ++m)                                                \
        _Pragma("unroll")                                                      \
        for (int n = 0; n < 4; ++n)                                            \
            acc[m][n] = __builtin_amdgcn_mfma_f32_16x16x32_bf16(               \
                af[m], bf[n], acc[m][n], 0, 0, 0);                             \
} while (0)

    // prologue: fill buffers 0 and 1 (8 loads in flight)
    STAGE(0);
    STAGE(1);

    int cur = 0;
    for (int ksi = 0; ksi < nsteps - 2; ++ksi) {
        const int nxt2 = (cur + 2 >= 3) ? cur - 1 : cur + 2;
        STAGE(nxt2);                     // +4 loads: 12 in flight
        asm volatile("s_waitcnt vmcnt(8)" ::: "memory");  // oldest 4 = buf cur
        __builtin_amdgcn_s_barrier();    // collective: buf cur ready
        COMPUTE(cur);                    // ds_read + 16 MFMA
        __builtin_amdgcn_s_barrier();    // readers done before overwrite
        cur = (cur + 1 >= 3) ? 0 : cur + 1;
    }
    // epilogue: two tiles left (bufs cur, cur+1), 8 loads outstanding
    asm volatile("s_waitcnt vmcnt(4)" ::: "memory");
    __builtin_amdgcn_s_barrier();
    COMPUTE(cur);
    __builtin_amdgcn_s_barrier();
    cur = (cur + 1 >= 3) ? 0 : cur + 1;
    asm volatile("s_waitcnt vmcnt(0)" ::: "memory");
    __builtin_amdgcn_s_barrier();
    COMPUTE(cur);

#undef STAGE
#undef COMPUTE

    // C/D layout: col = lane&15, row = (lane>>4)*4 + reg   [m89-verified]
    float* outp = part + (size_t)bz * N * N;
    const int rbase = i0 + (wave & 1) * 64 + (lane >> 4) * 4;
    const int cbase = j0 + (wave >> 1) * 64 + (lane & 15);
    #pragma unroll
    for (int m = 0; m < 4; ++m)
        #pragma unroll
        for (int n = 0; n < 4; ++n)
            #pragma unroll
            for (int r = 0; r < 4; ++r)
                outp[(size_t)(rbase + m * 16 + r) * N + cbase + n * 16] = acc[m][n][r];

    if (bx != by) {
        // mirror write: block collectively covers the full 128x128 transposed
        // region; L2 write-combining keeps HBM traffic at full-line granularity
        // [round-5/9/11 verified: WRITE_SIZE stayed at part size]
        #pragma unroll
        for (int m = 0; m < 4; ++m)
            #pragma unroll
            for (int n = 0; n < 4; ++n)
                #pragma unroll
                for (int r = 0; r < 4; ++r)
                    outp[(size_t)(cbase + n * 16) * N + rbase + m * 16 + r] = acc[m][n][r];
    }
}

// fused: sum split-K partials -> dist -> hardest pos/neg per row.
// 512 blocks x 2 rows; j-side labels loaded once per block.
template <int S>
__global__ __launch_bounds__(256)
void mine_kernel(const float* __restrict__ part,
                 const float* __restrict__ plab,
                 const int* __restrict__ glab,
                 float* __restrict__ rowloss) {
    const int i0 = blockIdx.x * 2;
    const int t = threadIdx.x;
    const int wave = t >> 6, lane = t & 63;
    const int j = t * 4;                       // this thread's 4 columns

    // j-side labels: loaded once, reused for both rows
    float labj[4][8];
    const float4* pj = (const float4*)&plab[(size_t)j * P];
    #pragma unroll
    for (int qq = 0; qq < 8; ++qq) ((float4*)labj)[qq] = pj[qq];
    const int4 gj = *(const int4*)&glab[j];
    const int gv[4] = {gj.x, gj.y, gj.z, gj.w};

    __shared__ float sap[4], san[4];

    #pragma unroll
    for (int ri = 0; ri < 2; ++ri) {
        const int i = i0 + ri;

        float4 dot = {0.f, 0.f, 0.f, 0.f};
        #pragma unroll
        for (int s = 0; s < S; ++s) {
            float4 v = *(const float4*)&part[(size_t)s * N * N + (size_t)i * N + j];
            dot.x += v.x; dot.y += v.y; dot.z += v.z; dot.w += v.w;
        }

        const int li = glab[i];
        float lab_i[P];
        #pragma unroll
        for (int c = 0; c < P; ++c) lab_i[c] = plab[i * P + c];

        float ap = -1e30f, an = 1e30f;
        const float dv[4] = {dot.x, dot.y, dot.z, dot.w};
        #pragma unroll
        for (int u = 0; u < 4; ++u) {
            float ov = 0.f;
            #pragma unroll
            for (int c = 0; c < P; ++c) ov += lab_i[c] * labj[u][c];
            float d = 0.5f - dv[u] / (2.0f * (ov + 1.0f));
            if (gv[u] == li) ap = fmaxf(ap, d);
            else             an = fminf(an, d);
        }

        #pragma unroll
        for (int m = 32; m > 0; m >>= 1) {
            ap = fmaxf(ap, __shfl_xor(ap, m, 64));
            an = fminf(an, __shfl_xor(an, m, 64));
        }
        if (lane == 0) { sap[wave] = ap; san[wave] = an; }
        __syncthreads();
        if (t == 0) {
            float A = fmaxf(fmaxf(sap[0], sap[1]), fmaxf(sap[2], sap[3]));
            float B = fminf(fminf(san[0], san[1]), fminf(san[2], san[3]));
            rowloss[i] = fmaxf(0.f, A - B + MARGIN);
        }
        __syncthreads();   // sap/san reusable next row
    }
}

__global__ void reduce_kernel(const float* __restrict__ rowloss,
                              float* __restrict__ out) {
    const int t = threadIdx.x;
    float s = rowloss[t] + rowloss[t + 256] + rowloss[t + 512] + rowloss[t + 768];
    __shared__ float red[256];
    red[t] = s;
    __syncthreads();
    for (int st = 128; st > 0; st >>= 1) {
        if (t < st) red[t] += red[t + st];
        __syncthreads();
    }
    if (t == 0) out[0] = red[0] * (1.0f / N);
}

extern "C" void kernel_launch(void* const* d_in, const int* in_sizes, int n_in,
                              void* d_out, int out_size, void* d_ws, size_t ws_size,
                              hipStream_t stream) {
    const float* gfeat = (const float*)d_in[0];
    const float* pfeat = (const float*)d_in[1];
    const float* plab  = (const float*)d_in[2];
    const int*   glab  = (const int*)d_in[3];
    float* out = (float*)d_out;

    const size_t vbytes = (size_t)N * KTOT * 2;     // 37,748,736
    const size_t slice  = (size_t)N * N * 4;        // 4 MB per split slice

    // split-K residency ladder: S=24 (3/CU resident) if workspace provably
    // allows, else S=16 (round-11/13 verified best), else S=8.
    int S;
    if (ws_size != 0 && ws_size >= vbytes + 24 * slice + 4096)       S = 24;
    else if (ws_size != 0 && ws_size >= vbytes + 16 * slice + 4096)  S = 16;
    else                                                             S = 8;
    const int ks = KTOT / S;                         // 768 / 1152 / 2304

    char* ws = (char*)d_ws;
    unsigned short* V = (unsigned short*)ws;
    float* part    = (float*)(ws + vbytes);
    float* rowloss = (float*)(ws + vbytes + (size_t)S * slice);

    pack_kernel<<<N * F / 4, 256, 0, stream>>>(gfeat, pfeat, plab, V);
    gemm_kernel<<<dim3(36, S), 256, 0, stream>>>(V, part, ks);
    if (S == 24)
        mine_kernel<24><<<N / 2, 256, 0, stream>>>(part, plab, glab, rowloss);
    else if (S == 16)
        mine_kernel<16><<<N / 2, 256, 0, stream>>>(part, plab, glab, rowloss);
    else
        mine_kernel<8><<<N / 2, 256, 0, stream>>>(part, plab, glab, rowloss);
    reduce_kernel<<<1, 256, 0, stream>>>(rowloss, out);
}

// Round 15
// 159.609 us; speedup vs baseline: 1.1049x; 1.1049x over previous
//
#include <hip/hip_runtime.h>

#define N 1024
#define D 2048
#define P 8
#define F 9
#define KTOT (F * D)          // 18432
#define BM 128                // tile M = N = 128
#define BKT 32                // K per step (16x16x32 MFMA)
#define MARGIN 0.3f

typedef float f32x4 __attribute__((ext_vector_type(4)));
typedef short s16x8 __attribute__((ext_vector_type(8)));

#define GLOBAL_AS __attribute__((address_space(1)))
#define LDS_AS __attribute__((address_space(3)))

__device__ __forceinline__ const float* feat_row(const float* __restrict__ g,
                                                 const float* __restrict__ p,
                                                 int i, int f) {
    return (f == 0) ? (g + (size_t)i * D)
                    : (p + ((size_t)i * P + (f - 1)) * D);
}

__device__ __forceinline__ unsigned f2bf(float x) {
    unsigned u = __float_as_uint(x);
    return (u + 0x7fffu + ((u >> 16) & 1u)) >> 16;   // RNE
}

// One WAVE per (i,f) row: sum-of-squares via shfl_xor (no barriers),
// scale by label/norm, convert to bf16, store V[(i*F+f)*D + k].
__global__ __launch_bounds__(256)
void pack_kernel(const float* __restrict__ gfeat,
                 const float* __restrict__ pfeat,
                 const float* __restrict__ plab,
                 unsigned short* __restrict__ V) {
    const int wid = (blockIdx.x << 2) | (threadIdx.x >> 6);  // row index i*F+f
    const int lane = threadIdx.x & 63;
    const int i = wid / F, f = wid % F;
    const float* src = feat_row(gfeat, pfeat, i, f);
    const float4* s4 = (const float4*)src;
    float4 a[4][2];
    #pragma unroll
    for (int q = 0; q < 4; ++q) {
        a[q][0] = s4[(q * 64 + lane) * 2];
        a[q][1] = s4[(q * 64 + lane) * 2 + 1];
    }
    float ss = 0.f;
    #pragma unroll
    for (int q = 0; q < 4; ++q)
        #pragma unroll
        for (int h = 0; h < 2; ++h)
            ss += a[q][h].x * a[q][h].x + a[q][h].y * a[q][h].y
                + a[q][h].z * a[q][h].z + a[q][h].w * a[q][h].w;
    #pragma unroll
    for (int m = 32; m > 0; m >>= 1) ss += __shfl_xor(ss, m, 64);
    const float ls = (f == 0) ? 1.0f : plab[i * P + (f - 1)];
    const float inv = ls / (sqrtf(ss) + 1e-12f);
    unsigned short* dst = V + (size_t)wid * D;
    #pragma unroll
    for (int q = 0; q < 4; ++q) {
        uint4 o;
        o.x = f2bf(a[q][0].x * inv) | (f2bf(a[q][0].y * inv) << 16);
        o.y = f2bf(a[q][0].z * inv) | (f2bf(a[q][0].w * inv) << 16);
        o.z = f2bf(a[q][1].x * inv) | (f2bf(a[q][1].y * inv) << 16);
        o.w = f2bf(a[q][1].z * inv) | (f2bf(a[q][1].w * inv) << 16);
        *(uint4*)&dst[(size_t)(q * 64 + lane) * 8] = o;
    }
}

// C = V * V^T, bf16 MFMA, 128x128 tile, runtime split-K, per-slice STORES.
// FINAL verified-best configuration (rounds 11/13: 45.5 us gemm, 161.6 total):
// - SYMMETRY: 36 upper-triangle tiles/slice, mirror-stored (r5)
// - XCD-chunked bijective swizzle (r2: FETCH 147->19 MB)
// - T2 XOR-swizzle, lane-linear staging (r8/9: SQ_LDS_BANK_CONFLICT = 0)
// - 3 LDS buffers (48 KB), depth-2 counted-vmcnt prefetch, 2 barriers/step
// Residency ladder fully mapped (r8-r14): 2 blocks/CU -> 54-55 us;
// 2.25 (S=16) -> 45.5 us BEST; 3.4 (S=24, +32 MB traffic) -> 51.2 us.
// Atomic accumulation epilogue: 227 MB write-through, 4.5x slower (r10).
__global__ __launch_bounds__(256)
void gemm_kernel(const unsigned short* __restrict__ V,
                 float* __restrict__ part, int ks) {
    __shared__ short As[3][BM * BKT];   // 3 x 8 KB
    __shared__ short Bs[3][BM * BKT];   // 3 x 8 KB  (48 KB total)

    // bijective XCD swizzle (nwg = 36*S, divisible by 8 for S=8/16)
    const int nwg = gridDim.x * gridDim.y;
    const int l = blockIdx.x + gridDim.x * blockIdx.y;
    const int q = nwg >> 3;
    const int wg = (l & 7) * q + (l >> 3);
    const int t36 = wg % 36;          // upper-triangle tile index
    const int bz = wg / 36;           // K-slice

    // t36 -> (by, bx) with by <= bx; row by holds (8-by) tiles
    int by = 0, rem = t36;
    while (rem >= 8 - by) { rem -= 8 - by; ++by; }
    const int bx = by + rem;

    const int t = threadIdx.x;
    const int wave = t >> 6, lane = t & 63;
    const int i0 = by * BM;
    const int j0 = bx * BM;
    const int kbase = bz * ks;
    const int nsteps = ks >> 5;      // ks/32: 36 (S=16) or 72 (S=8)

    // staging: thread t -> row t>>2 (and +64), slot t&3, source chunk XOR'd
    const int srow = t >> 2;
    const int schunk = (t & 3) ^ ((t >> 3) & 3);
    const unsigned short* Ag = V + (size_t)(i0 + srow) * KTOT + kbase + schunk * 8;
    const unsigned short* Bg = V + (size_t)(j0 + srow) * KTOT + kbase + schunk * 8;

    // fragment read: chunk K of row R at short offset R*32 + ((K^((R>>1)&3))*8)
    const int kq = lane >> 4;                       // K = 0..3
    const int rsw = ((lane & 15) >> 1) & 3;         // (R>>1)&3, uniform in m/n
    const int kk = (kq ^ rsw) * 8;                  // swizzled chunk offset (shorts)
    const int arow0 = (wave & 1) * 64 + (lane & 15);
    const int brow0 = (wave >> 1) * 64 + (lane & 15);

    f32x4 acc[4][4];
    #pragma unroll
    for (int m = 0; m < 4; ++m)
        #pragma unroll
        for (int n = 0; n < 4; ++n)
            acc[m][n] = (f32x4){0.f, 0.f, 0.f, 0.f};

#define STAGE(b) do {                                                          \
    __builtin_amdgcn_global_load_lds((const GLOBAL_AS void*)Ag,                \
        (LDS_AS void*)(&As[(b)][t * 8]), 16, 0, 0);                            \
    __builtin_amdgcn_global_load_lds((const GLOBAL_AS void*)(Ag + (size_t)64 * KTOT), \
        (LDS_AS void*)(&As[(b)][2048 + t * 8]), 16, 0, 0);                     \
    __builtin_amdgcn_global_load_lds((const GLOBAL_AS void*)Bg,                \
        (LDS_AS void*)(&Bs[(b)][t * 8]), 16, 0, 0);                            \
    __builtin_amdgcn_global_load_lds((const GLOBAL_AS void*)(Bg + (size_t)64 * KTOT), \
        (LDS_AS void*)(&Bs[(b)][2048 + t * 8]), 16, 0, 0);                     \
    Ag += BKT; Bg += BKT;                                                      \
} while (0)

#define COMPUTE(b) do {                                                        \
    s16x8 af[4], bf[4];                                                        \
    _Pragma("unroll")                                                          \
    for (int m = 0; m < 4; ++m)                                                \
        af[m] = *(const s16x8*)(&As[(b)][(arow0 + m * 16) * 32 + kk]);         \
    _Pragma("unroll")                                                          \
    for (int n = 0; n < 4; ++n)                                                \
        bf[n] = *(const s16x8*)(&Bs[(b)][(brow0 + n * 16) * 32 + kk]);         \
    _Pragma("unroll")                                                          \
    for (int m = 0; m < 4; ++m)                                                \
        _Pragma("unroll")                                                      \
        for (int n = 0; n < 4; ++n)                                            \
            acc[m][n] = __builtin_amdgcn_mfma_f32_16x16x32_bf16(               \
                af[m], bf[n], acc[m][n], 0, 0, 0);                             \
} while (0)

    // prologue: fill buffers 0 and 1 (8 loads in flight)
    STAGE(0);
    STAGE(1);

    int cur = 0;
    for (int ksi = 0; ksi < nsteps - 2; ++ksi) {
        const int nxt2 = (cur + 2 >= 3) ? cur - 1 : cur + 2;
        STAGE(nxt2);                     // +4 loads: 12 in flight
        asm volatile("s_waitcnt vmcnt(8)" ::: "memory");  // oldest 4 = buf cur
        __builtin_amdgcn_s_barrier();    // collective: buf cur ready
        COMPUTE(cur);                    // ds_read + 16 MFMA
        __builtin_amdgcn_s_barrier();    // readers done before overwrite
        cur = (cur + 1 >= 3) ? 0 : cur + 1;
    }
    // epilogue: two tiles left (bufs cur, cur+1), 8 loads outstanding
    asm volatile("s_waitcnt vmcnt(4)" ::: "memory");
    __builtin_amdgcn_s_barrier();
    COMPUTE(cur);
    __builtin_amdgcn_s_barrier();
    cur = (cur + 1 >= 3) ? 0 : cur + 1;
    asm volatile("s_waitcnt vmcnt(0)" ::: "memory");
    __builtin_amdgcn_s_barrier();
    COMPUTE(cur);

#undef STAGE
#undef COMPUTE

    // C/D layout: col = lane&15, row = (lane>>4)*4 + reg   [m89-verified]
    float* outp = part + (size_t)bz * N * N;
    const int rbase = i0 + (wave & 1) * 64 + (lane >> 4) * 4;
    const int cbase = j0 + (wave >> 1) * 64 + (lane & 15);
    #pragma unroll
    for (int m = 0; m < 4; ++m)
        #pragma unroll
        for (int n = 0; n < 4; ++n)
            #pragma unroll
            for (int r = 0; r < 4; ++r)
                outp[(size_t)(rbase + m * 16 + r) * N + cbase + n * 16] = acc[m][n][r];

    if (bx != by) {
        // mirror write: block collectively covers the full 128x128 transposed
        // region; L2 write-combining keeps HBM traffic at full-line granularity
        // [round-5/9/11 verified: WRITE_SIZE stayed 65.5 MB]
        #pragma unroll
        for (int m = 0; m < 4; ++m)
            #pragma unroll
            for (int n = 0; n < 4; ++n)
                #pragma unroll
                for (int r = 0; r < 4; ++r)
                    outp[(size_t)(cbase + n * 16) * N + rbase + m * 16 + r] = acc[m][n][r];
    }
}

// fused: sum split-K partials -> dist -> hardest pos/neg per row.
// 512 blocks x 2 rows; j-side labels loaded once per block.
template <int S>
__global__ __launch_bounds__(256)
void mine_kernel(const float* __restrict__ part,
                 const float* __restrict__ plab,
                 const int* __restrict__ glab,
                 float* __restrict__ rowloss) {
    const int i0 = blockIdx.x * 2;
    const int t = threadIdx.x;
    const int wave = t >> 6, lane = t & 63;
    const int j = t * 4;                       // this thread's 4 columns

    // j-side labels: loaded once, reused for both rows
    float labj[4][8];
    const float4* pj = (const float4*)&plab[(size_t)j * P];
    #pragma unroll
    for (int qq = 0; qq < 8; ++qq) ((float4*)labj)[qq] = pj[qq];
    const int4 gj = *(const int4*)&glab[j];
    const int gv[4] = {gj.x, gj.y, gj.z, gj.w};

    __shared__ float sap[4], san[4];

    #pragma unroll
    for (int ri = 0; ri < 2; ++ri) {
        const int i = i0 + ri;

        float4 dot = {0.f, 0.f, 0.f, 0.f};
        #pragma unroll
        for (int s = 0; s < S; ++s) {
            float4 v = *(const float4*)&part[(size_t)s * N * N + (size_t)i * N + j];
            dot.x += v.x; dot.y += v.y; dot.z += v.z; dot.w += v.w;
        }

        const int li = glab[i];
        float lab_i[P];
        #pragma unroll
        for (int c = 0; c < P; ++c) lab_i[c] = plab[i * P + c];

        float ap = -1e30f, an = 1e30f;
        const float dv[4] = {dot.x, dot.y, dot.z, dot.w};
        #pragma unroll
        for (int u = 0; u < 4; ++u) {
            float ov = 0.f;
            #pragma unroll
            for (int c = 0; c < P; ++c) ov += lab_i[c] * labj[u][c];
            float d = 0.5f - dv[u] / (2.0f * (ov + 1.0f));
            if (gv[u] == li) ap = fmaxf(ap, d);
            else             an = fminf(an, d);
        }

        #pragma unroll
        for (int m = 32; m > 0; m >>= 1) {
            ap = fmaxf(ap, __shfl_xor(ap, m, 64));
            an = fminf(an, __shfl_xor(an, m, 64));
        }
        if (lane == 0) { sap[wave] = ap; san[wave] = an; }
        __syncthreads();
        if (t == 0) {
            float A = fmaxf(fmaxf(sap[0], sap[1]), fmaxf(sap[2], sap[3]));
            float B = fminf(fminf(san[0], san[1]), fminf(san[2], san[3]));
            rowloss[i] = fmaxf(0.f, A - B + MARGIN);
        }
        __syncthreads();   // sap/san reusable next row
    }
}

__global__ void reduce_kernel(const float* __restrict__ rowloss,
                              float* __restrict__ out) {
    const int t = threadIdx.x;
    float s = rowloss[t] + rowloss[t + 256] + rowloss[t + 512] + rowloss[t + 768];
    __shared__ float red[256];
    red[t] = s;
    __syncthreads();
    for (int st = 128; st > 0; st >>= 1) {
        if (t < st) red[t] += red[t + st];
        __syncthreads();
    }
    if (t == 0) out[0] = red[0] * (1.0f / N);
}

extern "C" void kernel_launch(void* const* d_in, const int* in_sizes, int n_in,
                              void* d_out, int out_size, void* d_ws, size_t ws_size,
                              hipStream_t stream) {
    const float* gfeat = (const float*)d_in[0];
    const float* pfeat = (const float*)d_in[1];
    const float* plab  = (const float*)d_in[2];
    const int*   glab  = (const int*)d_in[3];
    float* out = (float*)d_out;

    const size_t vbytes = (size_t)N * KTOT * 2;     // 37,748,736
    const size_t slice  = (size_t)N * N * 4;        // 4 MB per split slice

    // split-K: S=16 is the measured optimum (r14: S=24 regressed via +32 MB
    // part traffic). Fall back to S=8 only if workspace can't hold 16 slices.
    int S = (ws_size != 0 && ws_size >= vbytes + 16 * slice + 4096) ? 16 : 8;
    const int ks = KTOT / S;                         // 1152 or 2304

    char* ws = (char*)d_ws;
    unsigned short* V = (unsigned short*)ws;
    float* part    = (float*)(ws + vbytes);
    float* rowloss = (float*)(ws + vbytes + (size_t)S * slice);

    pack_kernel<<<N * F / 4, 256, 0, stream>>>(gfeat, pfeat, plab, V);
    gemm_kernel<<<dim3(36, S), 256, 0, stream>>>(V, part, ks);
    if (S == 16)
        mine_kernel<16><<<N / 2, 256, 0, stream>>>(part, plab, glab, rowloss);
    else
        mine_kernel<8><<<N / 2, 256, 0, stream>>>(part, plab, glab, rowloss);
    reduce_kernel<<<1, 256, 0, stream>>>(rowloss, out);
}